// Round 3
// baseline (84.193 us; speedup 1.0000x reference)
//
#include <hip/hip_runtime.h>
#include <hip/hip_bf16.h>

// 4-qubit QNN: encoding RY(x) per sample + fixed variational block (shared
// weights) + <Z_q> readout.  The variational block is a constant 16x16
// unitary U; <Z_q> = s0^T Re(U^+ Z_q U) s0 with s0 a product state in
// v(t)=[cos(t/2),sin(t/2)].  Each output collapses to a 5x5 bilinear form
// in the degree-4 monomials of (c0,s0) and (c1,s1):
//   out_q = sum_{m,n} C[q][m][n] * c0^{4-m} s0^m * c1^{4-n} s1^n
//
// v4: R2 counters (VALUBusy 13%, Occupancy 19%, 117 cyc/sample vs ~5
// issue-bound) showed two latency pathologies:
//  1) per-block t<16 prologue -> all prologue waves pile on SIMD0 (4
//     blocks/CU) while 12 waves idle: fix = 256 blocks x 1024 threads
//     (ONE prologue per CU, 4x fewer replicas).
//  2) per-thread cf[100] cannot be register-resident (VGPR_Count=116) ->
//     compiler re-reads coeffs per FMA: fix = NO cf array; C stored in
//     LDS as [mn][q] float4 and read as 25 wave-uniform ds_read_b128
//     broadcasts per packed pair (conflict-free), each feeding 8 FMAs.

__device__ __forceinline__ float2 mul2(float2 a, float2 b) {
    return make_float2(a.x * b.x, a.y * b.y);
}
__device__ __forceinline__ float2 fma2(float s, float2 a, float2 b) {
    return make_float2(fmaf(s, a.x, b.x), fmaf(s, a.y, b.y));
}

__global__ __launch_bounds__(1024) void qnn_fused(const float4* __restrict__ x4,
                                                  const float* __restrict__ w,
                                                  float4* __restrict__ out,
                                                  int B) {
    __shared__ float Ur[16][16];
    __shared__ float Ui[16][16];
    __shared__ __align__(16) float Csh[100];   // layout: [mn][q], mn = m*5+n
    const int t = threadIdx.x;

    // ---- prologue: build C in LDS (proven math, one wave per block) ----
    if (t < 100) Csh[t] = 0.0f;

    if (t < 16) {
        // Thread t owns column t of U; left-multiplying U by a gate applies
        // the gate independently to each column.
        float ar[16], ai[16];
#pragma unroll
        for (int i = 0; i < 16; i++) { ar[i] = (i == t) ? 1.0f : 0.0f; ai[i] = 0.0f; }

#pragma unroll
        for (int l = 0; l < 3; l++) {
#pragma unroll
            for (int wq = 0; wq < 4; wq++) {
                const int st = 1 << (3 - wq);   // wire wq lives at bit (3-wq)
                float th, s, c;
                // RX(w[l][wq][0]):  a' = c*a - i s*b ; b' = -i s*a + c*b
                th = w[(l * 4 + wq) * 3 + 0] * 0.5f;
                __sincosf(th, &s, &c);
#pragma unroll
                for (int lo = 0; lo < 16; lo++) if (!(lo & st)) {
                    const int hi = lo | st;
                    const float arl = ar[lo], ail = ai[lo], arh = ar[hi], aih = ai[hi];
                    ar[lo] = c * arl + s * aih;
                    ai[lo] = c * ail - s * arh;
                    ar[hi] = c * arh + s * ail;
                    ai[hi] = c * aih - s * arl;
                }
                // RY(w[l][wq][1]):  a' = c*a - s*b ; b' = s*a + c*b (real)
                th = w[(l * 4 + wq) * 3 + 1] * 0.5f;
                __sincosf(th, &s, &c);
#pragma unroll
                for (int lo = 0; lo < 16; lo++) if (!(lo & st)) {
                    const int hi = lo | st;
                    const float arl = ar[lo], ail = ai[lo], arh = ar[hi], aih = ai[hi];
                    ar[lo] = c * arl - s * arh;
                    ai[lo] = c * ail - s * aih;
                    ar[hi] = s * arl + c * arh;
                    ai[hi] = s * ail + c * aih;
                }
                // RZ(w[l][wq][2]):  a' = (c - i s)*a ; b' = (c + i s)*b
                th = w[(l * 4 + wq) * 3 + 2] * 0.5f;
                __sincosf(th, &s, &c);
#pragma unroll
                for (int lo = 0; lo < 16; lo++) if (!(lo & st)) {
                    const int hi = lo | st;
                    const float arl = ar[lo], ail = ai[lo], arh = ar[hi], aih = ai[hi];
                    ar[lo] = c * arl + s * ail;
                    ai[lo] = c * ail - s * arl;
                    ar[hi] = c * arh - s * aih;
                    ai[hi] = c * aih + s * arh;
                }
            }
            // CNOT(i, (i+1)%4), i = 0..3, applied sequentially
#pragma unroll
            for (int ci = 0; ci < 4; ci++) {
                const int cst = 1 << (3 - ci);
                const int tst = 1 << (3 - ((ci + 1) & 3));
#pragma unroll
                for (int k = 0; k < 16; k++) if ((k & cst) && !(k & tst)) {
                    const int k2 = k | tst;
                    const float tr = ar[k], ti = ai[k];
                    ar[k] = ar[k2]; ai[k] = ai[k2];
                    ar[k2] = tr;    ai[k2] = ti;
                }
            }
        }
#pragma unroll
        for (int i = 0; i < 16; i++) { Ur[i][t] = ar[i]; Ui[i][t] = ai[i]; }
    }
    __syncthreads();

    // Thread t = i*16+j computes M_q[i][j] = Re(sum_k conj(U[k][i]) z_q(k) U[k][j])
    // and folds it into Csh[(mm*5+nn)*4 + q]; mm = popcount of x0-wire bits
    // of (i,j), nn = popcount of x1-wire bits.  Wires 0,2 (bits 3,1) carry
    // x0; wires 1,3 (bits 2,0) carry x1.
    if (t < 256) {
        const int i = t >> 4;
        const int j = t & 15;
        float m0 = 0.f, m1 = 0.f, m2 = 0.f, m3 = 0.f;
#pragma unroll
        for (int k = 0; k < 16; k++) {
            const float r = Ur[k][i] * Ur[k][j] + Ui[k][i] * Ui[k][j];
            m0 += ((k >> 3) & 1) ? -r : r;
            m1 += ((k >> 2) & 1) ? -r : r;
            m2 += ((k >> 1) & 1) ? -r : r;
            m3 += ((k >> 0) & 1) ? -r : r;
        }
        const int mm = ((i >> 3) & 1) + ((i >> 1) & 1) + ((j >> 3) & 1) + ((j >> 1) & 1);
        const int nn = ((i >> 2) & 1) + (i & 1) + ((j >> 2) & 1) + (j & 1);
        const int mn4 = (mm * 5 + nn) * 4;
        atomicAdd(&Csh[mn4 + 0], m0);
        atomicAdd(&Csh[mn4 + 1], m1);
        atomicAdd(&Csh[mn4 + 2], m2);
        atomicAdd(&Csh[mn4 + 3], m3);
    }
    __syncthreads();

    const float4* __restrict__ Csh4 = (const float4*)Csh;

    // ---- streaming phase: 4096 samples per block (4/thread) ----
    const int bs = blockIdx.x * 4096;

    if (bs + 4096 <= B) {
        // Fast path.  Each float4 x-load carries 2 samples; their angles are
        // packed into the x/y halves of float2 math.  Coefficients stream
        // from LDS as wave-uniform float4 broadcasts (no per-thread array).
#pragma unroll
        for (int k = 0; k < 2; k++) {
            const float4 f4 = x4[(bs >> 1) + k * 1024 + t];
            float2 s0, c0, s1, c1;
            __sincosf(f4.x * 0.5f, &s0.x, &c0.x);
            __sincosf(f4.z * 0.5f, &s0.y, &c0.y);
            __sincosf(f4.y * 0.5f, &s1.x, &c1.x);
            __sincosf(f4.w * 0.5f, &s1.y, &c1.y);

            const float2 cc0 = mul2(c0, c0), ss0 = mul2(s0, s0), cs0 = mul2(c0, s0);
            const float2 cc1 = mul2(c1, c1), ss1 = mul2(s1, s1), cs1 = mul2(c1, s1);
            const float2 p0[5] = { mul2(cc0, cc0), mul2(cc0, cs0), mul2(cs0, cs0),
                                   mul2(cs0, ss0), mul2(ss0, ss0) };
            const float2 p1[5] = { mul2(cc1, cc1), mul2(cc1, cs1), mul2(cs1, cs1),
                                   mul2(cs1, ss1), mul2(ss1, ss1) };

            float2 a0 = make_float2(0.f, 0.f), a1 = a0, a2 = a0, a3 = a0;
#pragma unroll
            for (int m = 0; m < 5; m++)
#pragma unroll
                for (int n = 0; n < 5; n++) {
                    const float4 cv = Csh4[m * 5 + n];     // ds_read_b128 broadcast
                    const float2 pp = mul2(p0[m], p1[n]);
                    a0 = fma2(cv.x, pp, a0);
                    a1 = fma2(cv.y, pp, a1);
                    a2 = fma2(cv.z, pp, a2);
                    a3 = fma2(cv.w, pp, a3);
                }
            const int s = bs + 2 * (k * 1024 + t);
            out[s]     = make_float4(a0.x, a1.x, a2.x, a3.x);
            out[s + 1] = make_float4(a0.y, a1.y, a2.y, a3.y);
        }
    } else {
        // Tail block: per-sample scalar path with bounds checks.
        const float2* __restrict__ x2 = (const float2*)x4;
#pragma unroll
        for (int k = 0; k < 4; k++) {
            const int s = bs + k * 1024 + t;
            if (s < B) {
                const float2 xv = x2[s];
                float st0, ct0, st1, ct1;
                __sincosf(xv.x * 0.5f, &st0, &ct0);
                __sincosf(xv.y * 0.5f, &st1, &ct1);
                const float cc0 = ct0 * ct0, ss0 = st0 * st0, cs0 = ct0 * st0;
                const float cc1 = ct1 * ct1, ss1 = st1 * st1, cs1 = ct1 * st1;
                const float q0[5] = { cc0 * cc0, cc0 * cs0, cs0 * cs0, cs0 * ss0, ss0 * ss0 };
                const float q1[5] = { cc1 * cc1, cc1 * cs1, cs1 * cs1, cs1 * ss1, ss1 * ss1 };
                float o0 = 0.f, o1 = 0.f, o2 = 0.f, o3 = 0.f;
#pragma unroll
                for (int m = 0; m < 5; m++)
#pragma unroll
                    for (int n = 0; n < 5; n++) {
                        const float4 cv = Csh4[m * 5 + n];
                        const float pp = q0[m] * q1[n];
                        o0 = fmaf(cv.x, pp, o0);
                        o1 = fmaf(cv.y, pp, o1);
                        o2 = fmaf(cv.z, pp, o2);
                        o3 = fmaf(cv.w, pp, o3);
                    }
                out[s] = make_float4(o0, o1, o2, o3);
            }
        }
    }
}

extern "C" void kernel_launch(void* const* d_in, const int* in_sizes, int n_in,
                              void* d_out, int out_size, void* d_ws, size_t ws_size,
                              hipStream_t stream) {
    const float* x = (const float*)d_in[0];      // (B, 2) float32
    const float* w = (const float*)d_in[1];      // (3, 4, 3) float32
    const int B = in_sizes[0] / 2;

    int grid = (B + 4095) / 4096;
    if (grid < 1) grid = 1;
    qnn_fused<<<grid, 1024, 0, stream>>>((const float4*)x, w, (float4*)d_out, B);
}

// Round 4
// 74.093 us; speedup vs baseline: 1.1363x; 1.1363x over previous
//
#include <hip/hip_runtime.h>
#include <hip/hip_bf16.h>

// 4-qubit QNN: encoding RY(x) per sample + fixed variational block (shared
// weights) + <Z_q> readout.  The variational block is a constant 16x16
// unitary U; <Z_q> = s0^T Re(U^+ Z_q U) s0 with s0 a product state in
// v(t)=[cos(t/2),sin(t/2)].  Each output collapses to a 5x5 bilinear form
// in the degree-4 monomials of (c0,s0) and (c1,s1):
//   out_q = sum_{m,n} C[q][m][n] * c0^{4-m} s0^m * c1^{4-n} s1^n
//
// v5: split kernels (best measured structure, R1=74.3us total) + the key
// fix: ALL 25 float4 coefficients are loaded into VGPRs BEFORE the sample
// loop, with __builtin_amdgcn_sched_barrier(0) preventing the compiler
// from sinking the loads into the loop (the R1/R2 pathology: VGPR=116
// proved cf[100] was not register-resident -> per-sample global reloads,
// VALUBusy 13%, 87% stall).  Inner loop now has zero memory traffic other
// than the x-load and out-store.  dur_us model from R1-R3: total =
// ~44us harness fill (fixed) + kernel time; target kernel ~5us.

__global__ __launch_bounds__(256) void qnn_setup(const float* __restrict__ w,
                                                 float* __restrict__ C_out) {
    __shared__ float Ur[16][16];
    __shared__ float Ui[16][16];
    __shared__ float Csh[100];   // layout [mn][q], mn = m*5+n
    const int t = threadIdx.x;

    if (t < 100) Csh[t] = 0.0f;

    if (t < 16) {
        // Thread t owns column t of U; left-multiplying U by a gate applies
        // the gate independently to each column.
        float ar[16], ai[16];
#pragma unroll
        for (int i = 0; i < 16; i++) { ar[i] = (i == t) ? 1.0f : 0.0f; ai[i] = 0.0f; }

#pragma unroll
        for (int l = 0; l < 3; l++) {
#pragma unroll
            for (int wq = 0; wq < 4; wq++) {
                const int st = 1 << (3 - wq);   // wire wq lives at bit (3-wq)
                float th, s, c;
                // RX(w[l][wq][0]):  a' = c*a - i s*b ; b' = -i s*a + c*b
                th = w[(l * 4 + wq) * 3 + 0] * 0.5f;
                __sincosf(th, &s, &c);
#pragma unroll
                for (int lo = 0; lo < 16; lo++) if (!(lo & st)) {
                    const int hi = lo | st;
                    const float arl = ar[lo], ail = ai[lo], arh = ar[hi], aih = ai[hi];
                    ar[lo] = c * arl + s * aih;
                    ai[lo] = c * ail - s * arh;
                    ar[hi] = c * arh + s * ail;
                    ai[hi] = c * aih - s * arl;
                }
                // RY(w[l][wq][1]):  a' = c*a - s*b ; b' = s*a + c*b (real)
                th = w[(l * 4 + wq) * 3 + 1] * 0.5f;
                __sincosf(th, &s, &c);
#pragma unroll
                for (int lo = 0; lo < 16; lo++) if (!(lo & st)) {
                    const int hi = lo | st;
                    const float arl = ar[lo], ail = ai[lo], arh = ar[hi], aih = ai[hi];
                    ar[lo] = c * arl - s * arh;
                    ai[lo] = c * ail - s * aih;
                    ar[hi] = s * arl + c * arh;
                    ai[hi] = s * ail + c * aih;
                }
                // RZ(w[l][wq][2]):  a' = (c - i s)*a ; b' = (c + i s)*b
                th = w[(l * 4 + wq) * 3 + 2] * 0.5f;
                __sincosf(th, &s, &c);
#pragma unroll
                for (int lo = 0; lo < 16; lo++) if (!(lo & st)) {
                    const int hi = lo | st;
                    const float arl = ar[lo], ail = ai[lo], arh = ar[hi], aih = ai[hi];
                    ar[lo] = c * arl + s * ail;
                    ai[lo] = c * ail - s * arl;
                    ar[hi] = c * arh - s * aih;
                    ai[hi] = c * aih + s * arh;
                }
            }
            // CNOT(i, (i+1)%4), i = 0..3, applied sequentially
#pragma unroll
            for (int ci = 0; ci < 4; ci++) {
                const int cst = 1 << (3 - ci);
                const int tst = 1 << (3 - ((ci + 1) & 3));
#pragma unroll
                for (int k = 0; k < 16; k++) if ((k & cst) && !(k & tst)) {
                    const int k2 = k | tst;
                    const float tr = ar[k], ti = ai[k];
                    ar[k] = ar[k2]; ai[k] = ai[k2];
                    ar[k2] = tr;    ai[k2] = ti;
                }
            }
        }
#pragma unroll
        for (int i = 0; i < 16; i++) { Ur[i][t] = ar[i]; Ui[i][t] = ai[i]; }
    }
    __syncthreads();

    // Thread t = i*16+j computes M_q[i][j] = Re(sum_k conj(U[k][i]) z_q(k) U[k][j])
    // and folds it into Csh[(mm*5+nn)*4 + q]; mm = popcount of x0-wire bits
    // of (i,j), nn = popcount of x1-wire bits.  Wires 0,2 (bits 3,1) carry
    // x0; wires 1,3 (bits 2,0) carry x1.
    {
        const int i = t >> 4;
        const int j = t & 15;
        float m0 = 0.f, m1 = 0.f, m2 = 0.f, m3 = 0.f;
#pragma unroll
        for (int k = 0; k < 16; k++) {
            const float r = Ur[k][i] * Ur[k][j] + Ui[k][i] * Ui[k][j];
            m0 += ((k >> 3) & 1) ? -r : r;
            m1 += ((k >> 2) & 1) ? -r : r;
            m2 += ((k >> 1) & 1) ? -r : r;
            m3 += ((k >> 0) & 1) ? -r : r;
        }
        const int mm = ((i >> 3) & 1) + ((i >> 1) & 1) + ((j >> 3) & 1) + ((j >> 1) & 1);
        const int nn = ((i >> 2) & 1) + (i & 1) + ((j >> 2) & 1) + (j & 1);
        const int mn4 = (mm * 5 + nn) * 4;
        atomicAdd(&Csh[mn4 + 0], m0);
        atomicAdd(&Csh[mn4 + 1], m1);
        atomicAdd(&Csh[mn4 + 2], m2);
        atomicAdd(&Csh[mn4 + 3], m3);
    }
    __syncthreads();
    if (t < 100) C_out[t] = Csh[t];
}

// ---------------------------------------------------------------------------
// Batch kernel: coefficients pinned in VGPRs, zero memory ops in the loop.

__device__ __forceinline__ float2 mul2(float2 a, float2 b) {
    return make_float2(a.x * b.x, a.y * b.y);
}
__device__ __forceinline__ float2 fma2(float s, float2 a, float2 b) {
    return make_float2(fmaf(s, a.x, b.x), fmaf(s, a.y, b.y));
}

__global__ __launch_bounds__(256) void qnn_batch(const float2* __restrict__ x2,
                                                 const float4* __restrict__ C4,
                                                 float4* __restrict__ out,
                                                 int B) {
    // Pin all 25 coefficient float4s ([mn][q] layout) in registers.  The
    // sched_barrier forbids sinking these loads into the sample loop.
    float4 cv[25];
#pragma unroll
    for (int i = 0; i < 25; i++) cv[i] = C4[i];
    __builtin_amdgcn_sched_barrier(0);

    const int t = threadIdx.x;
    const int bs = blockIdx.x * 1024;   // 1024 samples per block, 4/thread

    if (bs + 1024 <= B) {
        // Fast path: two packed iterations; each packs samples (sA, sA+256)
        // into the x/y halves of float2 math so every load and store
        // instruction is fully wave-contiguous.
#pragma unroll
        for (int k = 0; k < 2; k++) {
            const int sA = bs + k * 512 + t;
            const int sB = sA + 256;
            const float2 xA = x2[sA];
            const float2 xB = x2[sB];
            float2 s0, c0, s1, c1;
            __sincosf(xA.x * 0.5f, &s0.x, &c0.x);
            __sincosf(xB.x * 0.5f, &s0.y, &c0.y);
            __sincosf(xA.y * 0.5f, &s1.x, &c1.x);
            __sincosf(xB.y * 0.5f, &s1.y, &c1.y);

            const float2 cc0 = mul2(c0, c0), ss0 = mul2(s0, s0), cs0 = mul2(c0, s0);
            const float2 cc1 = mul2(c1, c1), ss1 = mul2(s1, s1), cs1 = mul2(c1, s1);
            const float2 p0[5] = { mul2(cc0, cc0), mul2(cc0, cs0), mul2(cs0, cs0),
                                   mul2(cs0, ss0), mul2(ss0, ss0) };
            const float2 p1[5] = { mul2(cc1, cc1), mul2(cc1, cs1), mul2(cs1, cs1),
                                   mul2(cs1, ss1), mul2(ss1, ss1) };

            float2 a0 = make_float2(0.f, 0.f), a1 = a0, a2 = a0, a3 = a0;
#pragma unroll
            for (int m = 0; m < 5; m++)
#pragma unroll
                for (int n = 0; n < 5; n++) {
                    const float4 cvv = cv[m * 5 + n];      // register, compile-time idx
                    const float2 pp = mul2(p0[m], p1[n]);
                    a0 = fma2(cvv.x, pp, a0);
                    a1 = fma2(cvv.y, pp, a1);
                    a2 = fma2(cvv.z, pp, a2);
                    a3 = fma2(cvv.w, pp, a3);
                }
            out[sA] = make_float4(a0.x, a1.x, a2.x, a3.x);
            out[sB] = make_float4(a0.y, a1.y, a2.y, a3.y);
        }
    } else {
        // Tail block: per-sample scalar path with bounds checks.
#pragma unroll
        for (int k = 0; k < 4; k++) {
            const int s = bs + k * 256 + t;
            if (s < B) {
                const float2 xv = x2[s];
                float st0, ct0, st1, ct1;
                __sincosf(xv.x * 0.5f, &st0, &ct0);
                __sincosf(xv.y * 0.5f, &st1, &ct1);
                const float cc0 = ct0 * ct0, ss0 = st0 * st0, cs0 = ct0 * st0;
                const float cc1 = ct1 * ct1, ss1 = st1 * st1, cs1 = ct1 * st1;
                const float q0[5] = { cc0 * cc0, cc0 * cs0, cs0 * cs0, cs0 * ss0, ss0 * ss0 };
                const float q1[5] = { cc1 * cc1, cc1 * cs1, cs1 * cs1, cs1 * ss1, ss1 * ss1 };
                float o0 = 0.f, o1 = 0.f, o2 = 0.f, o3 = 0.f;
#pragma unroll
                for (int m = 0; m < 5; m++)
#pragma unroll
                    for (int n = 0; n < 5; n++) {
                        const float4 cvv = cv[m * 5 + n];
                        const float pp = q0[m] * q1[n];
                        o0 = fmaf(cvv.x, pp, o0);
                        o1 = fmaf(cvv.y, pp, o1);
                        o2 = fmaf(cvv.z, pp, o2);
                        o3 = fmaf(cvv.w, pp, o3);
                    }
                out[s] = make_float4(o0, o1, o2, o3);
            }
        }
    }
}

extern "C" void kernel_launch(void* const* d_in, const int* in_sizes, int n_in,
                              void* d_out, int out_size, void* d_ws, size_t ws_size,
                              hipStream_t stream) {
    const float* x = (const float*)d_in[0];      // (B, 2) float32
    const float* w = (const float*)d_in[1];      // (3, 4, 3) float32
    float* C = (float*)d_ws;                     // 100 floats scratch, [mn][q]
    const int B = in_sizes[0] / 2;

    qnn_setup<<<1, 256, 0, stream>>>(w, C);

    int grid = (B + 1023) / 1024;
    if (grid < 1) grid = 1;
    qnn_batch<<<grid, 256, 0, stream>>>((const float2*)x, (const float4*)C,
                                        (float4*)d_out, B);
}